// Round 2
// baseline (279.417 us; speedup 1.0000x reference)
//
#include <hip/hip_runtime.h>

// spike_seq: (T=1024, B=16384, 2) fp32; w_exc: (1,2) = {0.7,1.0}; w_inh: -1.0.
// Outputs flat-concat: spk_rec (T*B) ++ mem_rec (T*B), fp32.
//
// Chunked-scan decomposition:
//   Phase 1: sequential carry scan (1 wave/CU, latency-hidden by 32-deep
//            rolling prefetch), stores (mem,inh) at every 32-step boundary
//            into d_ws (32 chunks x 16384 neurons x 2 floats = 4 MB).
//   Phase 2: 32-way parallel over chunks (32 waves/CU) replays each chunk
//            bit-identically and streams the outputs. BW-bound.
#define T_LEN  1024
#define B_N    16384
#define CHUNKS 32
#define CLEN   (T_LEN / CHUNKS)  // 32
#define D_PF   32                // phase-1 rolling prefetch depth

// One scan step. fp contract OFF: mul/add must round separately to match the
// numpy reference — an FMA-induced 1-ulp diff in mem near 1.0 flips a spike.
__device__ __forceinline__ void neuron_step(float x0, float x1,
                                            float w0, float w1, float wi,
                                            float& mem, float& inh, float& spk) {
#pragma clang fp contract(off)
  const float cur_exc = x0 * w0 + x1 * w1;   // w1 = 1.0 -> exact
  inh = 0.6f * inh + x0;
  const float cur = cur_exc + wi * inh;      // wi = -1.0 -> exact
  const float reset = (mem - 1.0f > 0.0f) ? 1.0f : 0.0f;  // prev-mem reset
  mem = 0.9f * mem + cur - reset * 1.0f;
  spk = (mem - 1.0f > 0.0f) ? 1.0f : 0.0f;
}

// Phase 1: one thread per neuron, full-T scan, carries only.
__global__ __launch_bounds__(64, 1) void FMFM_phase1_carry(
    const float* __restrict__ x, const float* __restrict__ w_exc,
    const float* __restrict__ w_inh, float* __restrict__ carry) {
#pragma clang fp contract(off)
  const int b = blockIdx.x * 64 + threadIdx.x;
  const float w0 = w_exc[0], w1 = w_exc[1], wi = w_inh[0];
  const float2* __restrict__ xp = (const float2*)x;

  float mem = 0.0f, inh = 0.0f;
  float spk;

  // Rolling circular prefetch buffer: always D_PF loads in flight.
  float2 buf[D_PF];
#pragma unroll
  for (int u = 0; u < D_PF; ++u) buf[u] = xp[u * B_N + b];

  // Main windows: refill slot u with t+D_PF right after consuming t.
  for (int t0 = 0; t0 < T_LEN - D_PF; t0 += D_PF) {
    const int c = t0 / CLEN;
    carry[c * B_N + b] = mem;                    // state BEFORE t = c*CLEN
    carry[CHUNKS * B_N + c * B_N + b] = inh;
#pragma unroll
    for (int u = 0; u < D_PF; ++u) {
      const float2 v = buf[u];
      buf[u] = xp[(t0 + u + D_PF) * B_N + b];    // keep depth at D_PF
      neuron_step(v.x, v.y, w0, w1, wi, mem, inh, spk);
    }
  }
  // Final window: no refill.
  {
    const int t0 = T_LEN - D_PF;
    const int c = t0 / CLEN;
    carry[c * B_N + b] = mem;
    carry[CHUNKS * B_N + c * B_N + b] = inh;
#pragma unroll
    for (int u = 0; u < D_PF; ++u)
      neuron_step(buf[u].x, buf[u].y, w0, w1, wi, mem, inh, spk);
  }
}

// Phase 2: one thread per (chunk, neuron); replay CLEN steps, store outputs.
__global__ __launch_bounds__(256) void FMFM_phase2_emit(
    const float* __restrict__ x, const float* __restrict__ w_exc,
    const float* __restrict__ w_inh, const float* __restrict__ carry,
    float* __restrict__ out) {
#pragma clang fp contract(off)
  const int c = blockIdx.x >> 6;                       // 64 neuron-blocks/chunk
  const int b = ((blockIdx.x & 63) << 8) + threadIdx.x;
  const float w0 = w_exc[0], w1 = w_exc[1], wi = w_inh[0];
  const float2* __restrict__ xp = (const float2*)x;

  float mem = carry[c * B_N + b];
  float inh = carry[CHUNKS * B_N + c * B_N + b];
  const int tbase = c * CLEN;

  // Issue all CLEN x-loads up front (pipelined drain via in-order vmcnt).
  float2 buf[CLEN];
#pragma unroll
  for (int u = 0; u < CLEN; ++u) buf[u] = xp[(tbase + u) * B_N + b];

  float* __restrict__ spk_out = out;
  float* __restrict__ mem_out = out + (size_t)T_LEN * B_N;
  float spk;
#pragma unroll
  for (int u = 0; u < CLEN; ++u) {
    const int t = tbase + u;
    neuron_step(buf[u].x, buf[u].y, w0, w1, wi, mem, inh, spk);
    // Non-temporal: keep the 134 MB write stream from evicting x in L2/LLC.
    __builtin_nontemporal_store(spk, &spk_out[t * B_N + b]);
    __builtin_nontemporal_store(mem, &mem_out[t * B_N + b]);
  }
}

extern "C" void kernel_launch(void* const* d_in, const int* in_sizes, int n_in,
                              void* d_out, int out_size, void* d_ws, size_t ws_size,
                              hipStream_t stream) {
  const float* x     = (const float*)d_in[0];
  const float* w_exc = (const float*)d_in[1];
  const float* w_inh = (const float*)d_in[2];
  float* out   = (float*)d_out;
  float* carry = (float*)d_ws;  // 2 * CHUNKS * B_N floats = 4 MB

  hipLaunchKernelGGL(FMFM_phase1_carry, dim3(B_N / 64), dim3(64), 0, stream,
                     x, w_exc, w_inh, carry);
  hipLaunchKernelGGL(FMFM_phase2_emit, dim3(CHUNKS * (B_N / 256)), dim3(256), 0,
                     stream, x, w_exc, w_inh, carry, out);
}

// Round 3
// 271.357 us; speedup vs baseline: 1.0297x; 1.0297x over previous
//
#include <hip/hip_runtime.h>

// spike_seq: (T=1024, B=16384, 2) fp32 with values EXACTLY 0.0f / 1.0f
// (uniform<0.05 cast). w_exc=(1,2)={0.7,1.0}; w_inh=-1.0.
// Outputs flat-concat: spk_rec (T*B) ++ mem_rec (T*B), fp32.
//
// 3-phase chunked scan exploiting binary inputs:
//  P0 pack: x -> 2-bit codes, 16 steps/u32  (134 MB read, 4 MB write, BW-bound)
//  P1 scan: sequential carry scan over the 4 MB bitmask (cache-resident;
//           VALU-issue-bound at 1 wave/CU, ~10 us instead of 80 us)
//  P2 emit: per-chunk replay from carries + bitmask, stream 268 MB out.
// Reconstructed (float)bit is bit-identical to the original 0.0f/1.0f, so
// the trajectory is exact.
#define T_LEN  1024
#define B_N    16384
#define CHUNKS 32
#define CLEN   (T_LEN / CHUNKS)   // 32 steps per phase-2 chunk
#define TPW    16                 // timesteps per packed u32 (2 bits each)
#define NTC    (T_LEN / TPW)      // 64 words per neuron
#define PF     8                  // phase-1 word prefetch depth (static-indexed)

// One scan step. fp contract OFF: mul/add must round separately to match the
// numpy reference — an FMA-induced 1-ulp diff in mem near 1.0 flips a spike.
__device__ __forceinline__ void neuron_step(float x0, float x1,
                                            float w0, float w1, float wi,
                                            float& mem, float& inh, float& spk) {
#pragma clang fp contract(off)
  const float cur_exc = x0 * w0 + x1 * w1;   // w1 = 1.0 -> exact
  inh = 0.6f * inh + x0;
  const float cur = cur_exc + wi * inh;      // wi = -1.0 -> exact
  const float reset = (mem - 1.0f > 0.0f) ? 1.0f : 0.0f;  // prev-mem reset
  mem = 0.9f * mem + cur - reset * 1.0f;
  spk = (mem - 1.0f > 0.0f) ? 1.0f : 0.0f;
}

// ---- Phase 0: pack x into 2-bit codes. Thread handles (tc, neuron-pair). ----
__global__ __launch_bounds__(256) void FMFM_pack(
    const float* __restrict__ x, unsigned* __restrict__ cbits) {
  const int tid = blockIdx.x * 256 + threadIdx.x;
  const int b2  = tid & (B_N / 2 - 1);   // neuron pair index (8192)
  const int tc  = tid >> 13;             // word index 0..NTC-1
  const float4* __restrict__ xp = (const float4*)x;  // (T, B/2) float4

  unsigned bits0 = 0, bits1 = 0;
#pragma unroll
  for (int u = 0; u < TPW; ++u) {
    const int t = tc * TPW + u;
    const float4 v = xp[(size_t)t * (B_N / 2) + b2];
    // v = {x0(2b2), x1(2b2), x0(2b2+1), x1(2b2+1)}
    bits0 |= ((v.x != 0.0f) ? 1u : 0u) << (2 * u);
    bits0 |= ((v.y != 0.0f) ? 2u : 0u) << (2 * u);
    bits1 |= ((v.z != 0.0f) ? 1u : 0u) << (2 * u);
    bits1 |= ((v.w != 0.0f) ? 2u : 0u) << (2 * u);
  }
  uint2 w; w.x = bits0; w.y = bits1;
  *(uint2*)&cbits[(size_t)tc * B_N + 2 * b2] = w;  // 8B/lane, coalesced
}

// ---- Phase 1: sequential carry scan over the bitmask. 1 thread/neuron. ----
__global__ __launch_bounds__(64, 1) void FMFM_scan(
    const unsigned* __restrict__ cbits, const float* __restrict__ w_exc,
    const float* __restrict__ w_inh, float* __restrict__ carry) {
#pragma clang fp contract(off)
  const int b = blockIdx.x * 64 + threadIdx.x;
  const float w0 = w_exc[0], w1 = w_exc[1], wi = w_inh[0];
  float mem = 0.0f, inh = 0.0f, spk;

  unsigned buf[PF];
#pragma unroll
  for (int i = 0; i < PF; ++i) buf[i] = cbits[i * B_N + b];

  for (int tc0 = 0; tc0 < NTC; tc0 += PF) {     // 8 windows of 8 words
#pragma unroll
    for (int i = 0; i < PF; ++i) {
      const int tc = tc0 + i;
      if ((tc & 1) == 0) {                      // chunk boundary (CLEN=2 words)
        const int c = tc >> 1;
        carry[c * B_N + b] = mem;               // state BEFORE t = c*CLEN
        carry[(CHUNKS + c) * B_N + b] = inh;
      }
      const unsigned w = buf[i];
      int nx = tc + PF; if (nx > NTC - 1) nx = NTC - 1;   // clamped refill
      buf[i] = cbits[nx * B_N + b];
#pragma unroll
      for (int u = 0; u < TPW; ++u) {
        const float x0 = (float)((w >> (2 * u)) & 1u);
        const float x1 = (float)((w >> (2 * u + 1)) & 1u);
        neuron_step(x0, x1, w0, w1, wi, mem, inh, spk);
      }
    }
  }
}

// ---- Phase 2: per-chunk replay + output streaming. ----
__global__ __launch_bounds__(256) void FMFM_emit(
    const unsigned* __restrict__ cbits, const float* __restrict__ w_exc,
    const float* __restrict__ w_inh, const float* __restrict__ carry,
    float* __restrict__ out) {
#pragma clang fp contract(off)
  const int c = blockIdx.x >> 6;                       // 64 neuron-blocks/chunk
  const int b = ((blockIdx.x & 63) << 8) + threadIdx.x;
  const float w0 = w_exc[0], w1 = w_exc[1], wi = w_inh[0];

  float mem = carry[c * B_N + b];
  float inh = carry[(CHUNKS + c) * B_N + b];
  const unsigned wa = cbits[(2 * c) * B_N + b];        // steps 0..15 of chunk
  const unsigned wb = cbits[(2 * c + 1) * B_N + b];    // steps 16..31

  float* __restrict__ spk_out = out;
  float* __restrict__ mem_out = out + (size_t)T_LEN * B_N;
  const int tbase = c * CLEN;
  float spk;

#pragma unroll
  for (int u = 0; u < CLEN; ++u) {
    const unsigned w = (u < TPW) ? wa : wb;
    const int s = u & (TPW - 1);
    const float x0 = (float)((w >> (2 * s)) & 1u);
    const float x1 = (float)((w >> (2 * s + 1)) & 1u);
    neuron_step(x0, x1, w0, w1, wi, mem, inh, spk);
    const int t = tbase + u;
    // Non-temporal: keep the 268 MB write stream out of L2/LLC.
    __builtin_nontemporal_store(spk, &spk_out[t * B_N + b]);
    __builtin_nontemporal_store(mem, &mem_out[t * B_N + b]);
  }
}

extern "C" void kernel_launch(void* const* d_in, const int* in_sizes, int n_in,
                              void* d_out, int out_size, void* d_ws, size_t ws_size,
                              hipStream_t stream) {
  const float* x     = (const float*)d_in[0];
  const float* w_exc = (const float*)d_in[1];
  const float* w_inh = (const float*)d_in[2];
  float* out = (float*)d_out;

  unsigned* cbits = (unsigned*)d_ws;                       // 4 MB
  float*    carry = (float*)((char*)d_ws + (size_t)NTC * B_N * 4);  // 4 MB

  hipLaunchKernelGGL(FMFM_pack, dim3(NTC * (B_N / 2) / 256), dim3(256), 0,
                     stream, x, cbits);
  hipLaunchKernelGGL(FMFM_scan, dim3(B_N / 64), dim3(64), 0, stream,
                     cbits, w_exc, w_inh, carry);
  hipLaunchKernelGGL(FMFM_emit, dim3(CHUNKS * (B_N / 256)), dim3(256), 0,
                     stream, cbits, w_exc, w_inh, carry, out);
}

// Round 4
// 266.576 us; speedup vs baseline: 1.0482x; 1.0179x over previous
//
#include <hip/hip_runtime.h>

// spike_seq: (T=1024, B=16384, 2) fp32 with values EXACTLY 0.0f / 1.0f.
// w_exc=(1,2)={0.7,1.0}; w_inh=-1.0.
// Outputs flat-concat: spk_rec (T*B) ++ mem_rec (T*B), fp32.
//
// 3-phase chunked scan exploiting binary inputs (bit-exact reconstruction):
//  P0 pack: x -> 2-bit codes, 16 steps/u32  (134 MB read, 4 MB write)
//  P1 scan: sequential carry scan over the 4 MB bitmask. 1 wave/CU.
//           Round-4 fix: pure load stream (carries buffered in LDS, not
//           global -> no store pollution of vmcnt), static refill indices,
//           PF=16 (256-step lookahead per slot).
//  P2 emit: per-chunk replay from carries + bitmask, stream 134 MB out (NT).
#define T_LEN  1024
#define B_N    16384
#define CHUNKS 32
#define CLEN   (T_LEN / CHUNKS)   // 32 steps per phase-2 chunk
#define TPW    16                 // timesteps per packed u32 (2 bits each)
#define NTC    (T_LEN / TPW)      // 64 words per neuron
#define PF     16                 // phase-1 rolling prefetch depth (words)

// One scan step. fp contract OFF: mul/add must round separately to match the
// numpy reference — an FMA-induced 1-ulp diff in mem near 1.0 flips a spike.
__device__ __forceinline__ void neuron_step(float x0, float x1,
                                            float w0, float w1, float wi,
                                            float& mem, float& inh, float& spk) {
#pragma clang fp contract(off)
  const float cur_exc = x0 * w0 + x1 * w1;   // w1 = 1.0 -> exact
  inh = 0.6f * inh + x0;
  const float cur = cur_exc + wi * inh;      // wi = -1.0 -> exact
  const float reset = (mem - 1.0f > 0.0f) ? 1.0f : 0.0f;  // prev-mem reset
  mem = 0.9f * mem + cur - reset * 1.0f;
  spk = (mem - 1.0f > 0.0f) ? 1.0f : 0.0f;
}

__device__ __forceinline__ void word_steps16(unsigned w, float w0, float w1,
                                             float wi, float& mem, float& inh,
                                             float& spk) {
#pragma unroll
  for (int u = 0; u < TPW; ++u) {
    const float x0 = (float)((w >> (2 * u)) & 1u);
    const float x1 = (float)((w >> (2 * u + 1)) & 1u);
    neuron_step(x0, x1, w0, w1, wi, mem, inh, spk);
  }
}

// ---- Phase 0: pack x into 2-bit codes. Thread handles (tc, neuron-pair). ----
__global__ __launch_bounds__(256) void FMFM_pack(
    const float* __restrict__ x, unsigned* __restrict__ cbits) {
  const int tid = blockIdx.x * 256 + threadIdx.x;
  const int b2  = tid & (B_N / 2 - 1);   // neuron pair index (8192)
  const int tc  = tid >> 13;             // word index 0..NTC-1
  const float4* __restrict__ xp = (const float4*)x;  // (T, B/2) float4

  unsigned bits0 = 0, bits1 = 0;
#pragma unroll
  for (int u = 0; u < TPW; ++u) {
    const int t = tc * TPW + u;
    const float4 v = xp[(size_t)t * (B_N / 2) + b2];
    bits0 |= ((v.x != 0.0f) ? 1u : 0u) << (2 * u);
    bits0 |= ((v.y != 0.0f) ? 2u : 0u) << (2 * u);
    bits1 |= ((v.z != 0.0f) ? 1u : 0u) << (2 * u);
    bits1 |= ((v.w != 0.0f) ? 2u : 0u) << (2 * u);
  }
  uint2 w; w.x = bits0; w.y = bits1;
  *(uint2*)&cbits[(size_t)tc * B_N + 2 * b2] = w;  // 8B/lane, coalesced
}

// ---- Phase 1: sequential carry scan over the bitmask. 1 thread/neuron,
//      64-thread blocks, 256 blocks = 1 wave/CU. Pure-load vmcnt stream. ----
__global__ __launch_bounds__(64, 1) void FMFM_scan(
    const unsigned* __restrict__ cbits, const float* __restrict__ w_exc,
    const float* __restrict__ w_inh, float* __restrict__ carry) {
#pragma clang fp contract(off)
  const int b = blockIdx.x * 64 + threadIdx.x;
  const int lt = threadIdx.x;
  const float w0 = w_exc[0], w1 = w_exc[1], wi = w_inh[0];
  float mem = 0.0f, inh = 0.0f, spk;

  // Carries buffered in LDS (lgkmcnt domain — keeps vmcnt loads unpolluted).
  __shared__ float lcar[2 * CHUNKS * 64];  // 16 KB: [(c*2+{0,1})*64 + lane]

  unsigned buf[PF];
#pragma unroll
  for (int i = 0; i < PF; ++i) buf[i] = cbits[i * B_N + b];

  // Full windows with unconditional, statically-sloted refills.
  for (int tc0 = 0; tc0 < NTC - PF; tc0 += PF) {  // tc0 = 0,16,32
#pragma unroll
    for (int i = 0; i < PF; ++i) {
      const int tc = tc0 + i;
      if ((i & 1) == 0) {                         // tc even: chunk boundary
        const int c = tc >> 1;
        lcar[(2 * c + 0) * 64 + lt] = mem;        // state BEFORE t = c*CLEN
        lcar[(2 * c + 1) * 64 + lt] = inh;
      }
      const unsigned w = buf[i];
      buf[i] = cbits[(tc + PF) * B_N + b];        // keep depth at PF
      word_steps16(w, w0, w1, wi, mem, inh, spk);
    }
  }
  // Final window: no refills.
#pragma unroll
  for (int i = 0; i < PF; ++i) {
    const int tc = (NTC - PF) + i;
    if ((i & 1) == 0) {
      const int c = tc >> 1;
      lcar[(2 * c + 0) * 64 + lt] = mem;
      lcar[(2 * c + 1) * 64 + lt] = inh;
    }
    word_steps16(buf[i], w0, w1, wi, mem, inh, spk);
  }
  // Flush carries to global once, coalesced.
#pragma unroll
  for (int c = 0; c < CHUNKS; ++c) {
    carry[c * B_N + b]            = lcar[(2 * c + 0) * 64 + lt];
    carry[(CHUNKS + c) * B_N + b] = lcar[(2 * c + 1) * 64 + lt];
  }
}

// ---- Phase 2: per-chunk replay + output streaming. ----
__global__ __launch_bounds__(256) void FMFM_emit(
    const unsigned* __restrict__ cbits, const float* __restrict__ w_exc,
    const float* __restrict__ w_inh, const float* __restrict__ carry,
    float* __restrict__ out) {
#pragma clang fp contract(off)
  const int c = blockIdx.x >> 6;                       // 64 neuron-blocks/chunk
  const int b = ((blockIdx.x & 63) << 8) + threadIdx.x;
  const float w0 = w_exc[0], w1 = w_exc[1], wi = w_inh[0];

  float mem = carry[c * B_N + b];
  float inh = carry[(CHUNKS + c) * B_N + b];
  const unsigned wa = cbits[(2 * c) * B_N + b];        // steps 0..15 of chunk
  const unsigned wb = cbits[(2 * c + 1) * B_N + b];    // steps 16..31

  float* __restrict__ spk_out = out;
  float* __restrict__ mem_out = out + (size_t)T_LEN * B_N;
  const int tbase = c * CLEN;
  float spk;

#pragma unroll
  for (int u = 0; u < CLEN; ++u) {
    const unsigned w = (u < TPW) ? wa : wb;
    const int s = u & (TPW - 1);
    const float x0 = (float)((w >> (2 * s)) & 1u);
    const float x1 = (float)((w >> (2 * s + 1)) & 1u);
    neuron_step(x0, x1, w0, w1, wi, mem, inh, spk);
    const int t = tbase + u;
    // Non-temporal: keep the 134 MB write stream out of L2/LLC.
    __builtin_nontemporal_store(spk, &spk_out[t * B_N + b]);
    __builtin_nontemporal_store(mem, &mem_out[t * B_N + b]);
  }
}

extern "C" void kernel_launch(void* const* d_in, const int* in_sizes, int n_in,
                              void* d_out, int out_size, void* d_ws, size_t ws_size,
                              hipStream_t stream) {
  const float* x     = (const float*)d_in[0];
  const float* w_exc = (const float*)d_in[1];
  const float* w_inh = (const float*)d_in[2];
  float* out = (float*)d_out;

  unsigned* cbits = (unsigned*)d_ws;                                // 4 MB
  float*    carry = (float*)((char*)d_ws + (size_t)NTC * B_N * 4);  // 4 MB

  hipLaunchKernelGGL(FMFM_pack, dim3(NTC * (B_N / 2) / 256), dim3(256), 0,
                     stream, x, cbits);
  hipLaunchKernelGGL(FMFM_scan, dim3(B_N / 64), dim3(64), 0, stream,
                     cbits, w_exc, w_inh, carry);
  hipLaunchKernelGGL(FMFM_emit, dim3(CHUNKS * (B_N / 256)), dim3(256), 0,
                     stream, cbits, w_exc, w_inh, carry, out);
}